// Round 11
// baseline (291.744 us; speedup 1.0000x reference)
//
#include <hip/hip_runtime.h>
#include <hip/hip_bf16.h>

#define B_ 4096
#define D_ 1024
#define H_ 8192
#define O_ 1000
#define K2 2048          // physical packed K ([hi|lo])
#define NT 96            // logical K-tiles: 3072 / 32

typedef __attribute__((ext_vector_type(8))) short short8;
typedef __attribute__((ext_vector_type(4))) short short4v;
typedef __attribute__((ext_vector_type(16))) float f32x16;

union BF4 { __hip_bfloat16 b[4]; short4v s; };

__device__ __forceinline__ void gload16(void* ldsp, const void* g) {
  __builtin_amdgcn_global_load_lds(
      (const __attribute__((address_space(1))) unsigned int*)g,
      (__attribute__((address_space(3))) unsigned int*)ldsp, 16, 0, 0);
}

// K-tile T (32 k) -> column offset in packed [hi|lo] rows. bf16x3 interleave
// on 64-k granules g = T>>1: r0 = xh*wh, r1 = xl*wh, r2 = xh*wl.
__device__ __forceinline__ int aoff32_(int T) {
  const int g = T >> 1, t = g / 3, r = g - 3 * t;
  return (r == 1 ? 1024 : 0) + t * 64 + (T & 1) * 32;
}
__device__ __forceinline__ int boff32_(int T) {
  const int g = T >> 1, t = g / 3, r = g - 3 * t;
  return (r == 2 ? 1024 : 0) + t * 64 + (T & 1) * 32;
}

// ---- merged split: fp32 -> [hi|lo] bf16 + sum-of-squares + keys init ----
__global__ __launch_bounds__(256) void split_all_kernel(
    const float* __restrict__ x, const float* __restrict__ w,
    __hip_bfloat16* __restrict__ Ap, __hip_bfloat16* __restrict__ Bp,
    float* __restrict__ xsq, float* __restrict__ wsq,
    unsigned long long* __restrict__ keys)
{
  const int r = blockIdx.x;
  const int t = threadIdx.x;
  const float* src;
  __hip_bfloat16* dst;
  float* sq;
  if (r < B_) {
    src = x + (size_t)r * D_; dst = Ap + (size_t)r * K2; sq = xsq + r;
    if (t == 0) keys[r] = ~0ULL;
  } else {
    const int rr = r - B_;
    src = w + (size_t)rr * D_; dst = Bp + (size_t)rr * K2; sq = wsq + rr;
  }
  const float4 v = ((const float4*)src)[t];
  float ss = v.x * v.x + v.y * v.y + v.z * v.z + v.w * v.w;

  BF4 Hh, Ll;
  const float e[4] = {v.x, v.y, v.z, v.w};
#pragma unroll
  for (int i = 0; i < 4; ++i) {
    __hip_bfloat16 h = __float2bfloat16(e[i]);
    Hh.b[i] = h;
    Ll.b[i] = __float2bfloat16(e[i] - __bfloat162float(h));
  }
  *(short4v*)(dst + t * 4) = Hh.s;
  *(short4v*)(dst + 1024 + t * 4) = Ll.s;

#pragma unroll
  for (int o = 32; o > 0; o >>= 1) ss += __shfl_down(ss, o);
  __shared__ float wsum[4];
  if ((t & 63) == 0) wsum[t >> 6] = ss;
  __syncthreads();
  if (t == 0) *sq = (wsum[0] + wsum[1]) + (wsum[2] + wsum[3]);
}

// ---- 256x256 GEMM, BK=32, 4 LDS buffers, ALL-COUNTED gates ----
// Buf b (32 KB) at b*32768: A 256 rows x 32k @ +0 (64B rows),
// B 256 cols x 32k @ +16384. Swizzle: phys 16B-unit = logical ^ f(row),
// f(row) = (row>>3)&3  [stride-8 lane groups 2-way=free; consecutive-8
// groups same-address broadcast] applied via pre-swizzled global source.
// Tile T (2 kk-phases): 6 asm ds_reads + 8 mfma_32x32x16 per phase,
// reads 1 phase ahead (lgkmcnt(6) ping-pong). Stage tile T+3 during T
// (A x2 gloads at ph0, B x2 at ph1) into buf (T-1)&3 — WAR-safe: all
// buf(T-1) reads lgkm-drained before end-of-(T-1) barrier.
// End-of-tile gate vmcnt(4): drains T+2's stages (certifies buf(T+2)
// for T+1.ph1's read-ahead), leaves T+3's 4 in flight. NEVER 0 until
// the last 3 tiles.

#define BAR() do { asm volatile("" ::: "memory"); \
                   __builtin_amdgcn_s_barrier(); \
                   asm volatile("" ::: "memory"); } while (0)
#define SB0() __builtin_amdgcn_sched_barrier(0)
#define GATE_S(S) asm volatile("s_waitcnt vmcnt(" S ")" ::: "memory")
#define LGKM6() do { asm volatile("s_waitcnt lgkmcnt(6)"); SB0(); } while (0)
#define LGKM0() do { asm volatile("s_waitcnt lgkmcnt(0)"); SB0(); } while (0)

#define DSR(dst, base, OFF) \
  asm volatile("ds_read_b128 %0, %1 offset:" OFF : "=v"(dst) : "v"(base))

// 6 reads for kk-granule KK: 4 A (m*32 rows) + 2 B (n*32 cols)
#define RDP(F, DSEL, KK) do { \
    const unsigned a_ = aB + (DSEL) + ofk##KK; \
    const unsigned b_ = bB + (DSEL) + ofk##KK; \
    DSR(F[0], a_, "0");    DSR(F[1], a_, "2048"); \
    DSR(F[2], a_, "4096"); DSR(F[3], a_, "6144"); \
    DSR(F[4], b_, "0");    DSR(F[5], b_, "2048"); \
  } while (0)

// Stage A / B of tile T: 2 gloads each; linear LDS dst, swizzled source.
#define STAGE_A(T) do { \
    const int ka_ = aoff32_(T); \
    char* d_ = lds + ((T)&3)*32768 + wid*2048 + lane*16; \
    gload16(d_,        gA0 + ka_); \
    gload16(d_ + 1024, gA1 + ka_); } while (0)
#define STAGE_B(T) do { \
    const int kb_ = boff32_(T); \
    char* d_ = lds + ((T)&3)*32768 + 16384 + wid*2048 + lane*16; \
    gload16(d_,        gB0 + kb_); \
    gload16(d_ + 1024, gB1 + kb_); } while (0)

#define MFMA32(a, b, c) __builtin_amdgcn_mfma_f32_32x32x16_bf16(a, b, c, 0, 0, 0)

#define MMQ32(F) do { \
    __builtin_amdgcn_s_setprio(1); \
    acc[0][0] = MFMA32(F[0], F[4], acc[0][0]); \
    acc[0][1] = MFMA32(F[0], F[5], acc[0][1]); \
    acc[1][0] = MFMA32(F[1], F[4], acc[1][0]); \
    acc[1][1] = MFMA32(F[1], F[5], acc[1][1]); \
    acc[2][0] = MFMA32(F[2], F[4], acc[2][0]); \
    acc[2][1] = MFMA32(F[2], F[5], acc[2][1]); \
    acc[3][0] = MFMA32(F[3], F[4], acc[3][0]); \
    acc[3][1] = MFMA32(F[3], F[5], acc[3][1]); \
    __builtin_amdgcn_s_setprio(0); \
    SB0(); } while (0)

// One tile = 2 phases. DSEL/D1SEL compile-time buf byte offsets.
// DOSTAGE: stage tile T+3. GS: end-of-tile gate count. DONEXT: read T+1.
#define TILE(DSEL, D1SEL, T, DOSTAGE, GS, DONEXT) do { \
    /* ph0: MFMA(kk0) on f0; read kk1; stage A(T+3) */ \
    RDP(f1, DSEL, 1); \
    if (DOSTAGE) STAGE_A((T) + 3); \
    LGKM6(); \
    MMQ32(f0); \
    /* ph1: MFMA(kk1) on f1; read next tile kk0; stage B(T+3) */ \
    if (DONEXT) RDP(f0, D1SEL, 0); \
    if (DOSTAGE) STAGE_B((T) + 3); \
    if (DONEXT) { LGKM6(); } else { LGKM0(); } \
    MMQ32(f1); \
    GATE_S(GS); BAR(); \
  } while (0)

__global__ __launch_bounds__(512, 2) void gemm_argmin_kernel(
    const __hip_bfloat16* __restrict__ Ap, const __hip_bfloat16* __restrict__ Bp,
    const float* __restrict__ xsq, const float* __restrict__ wsq,
    unsigned long long* __restrict__ keys)
{
  __shared__ char lds[131072];

  const int t = threadIdx.x;
  // XCD-aware: square 8x8 tile-chunk per XCD (r4-proven).
  const int id = blockIdx.x;
  const int xcd = id & 7;
  const int r_ = id >> 3;
  const int by = (xcd >> 2) * 8 + (r_ >> 3);
  const int bx = (xcd & 3) * 8 + (r_ & 7);
  const int brow = by * 256, bcol = bx * 256;

  const int lane = t & 63, wid = t >> 6;
  const int wm = wid >> 2, wn = wid & 3;   // wave tile 128 rows x 64 cols
  const int c31 = lane & 31;               // frag row/col
  const int kh = lane >> 5;                // k-half within 16-k granule
  const unsigned fsw = (unsigned)((c31 >> 3) & 3);  // f(row), row = c31 mod 32

  // swizzled 16B-unit offsets: tile has 4 units; kk granule uses units 2kk+kh
  const unsigned ofk0 = (((0u + kh) ^ fsw) * 16);
  const unsigned ofk1 = (((2u + kh) ^ fsw) * 16);

  const unsigned lb = (unsigned)(uintptr_t)lds;
  const unsigned aB = lb + (unsigned)(wm * 8192 + c31 * 64);
  const unsigned bB = lb + (unsigned)(16384 + wn * 4096 + c31 * 64);

  // staging source geometry: gload g covers rows wid*32 + g*16 + (lane>>2),
  // phys unit (lane&3) holds logical (lane&3) ^ f(row),
  // f(row) = (2g + (lane>>5)) & 3  (wid*32 contributes 0 mod 4).
  const int sr = lane >> 2;
  const int su0 = (lane & 3) ^ (lane >> 5);        // g=0
  const int su1 = su0 ^ 2;                         // g=1
  const __hip_bfloat16* gA0 = Ap + (size_t)(brow + wid * 32 + sr) * K2 + su0 * 8;
  const __hip_bfloat16* gA1 = Ap + (size_t)(brow + wid * 32 + 16 + sr) * K2 + su1 * 8;
  const __hip_bfloat16* gB0 = Bp + (size_t)(bcol + wid * 32 + sr) * K2 + su0 * 8;
  const __hip_bfloat16* gB1 = Bp + (size_t)(bcol + wid * 32 + 16 + sr) * K2 + su1 * 8;

  f32x16 acc[4][2] = {};
  short8 f0[6], f1[6];

  // Prologue: stage tiles 0,1,2 (12 gloads); certify bufs 0,1; preload f0.
  STAGE_A(0); STAGE_B(0);
  STAGE_A(1); STAGE_B(1);
  STAGE_A(2); STAGE_B(2);
  GATE_S("4");          // drains tiles 0,1 (8 oldest); tile2's 4 in flight
  BAR();
  RDP(f0, 0, 0);        // tile0 kk0
  SB0();

  for (int tb = 0; tb < NT - 4; tb += 4) {
    TILE(0,     32768, tb + 0, 1, "4", 1);
    TILE(32768, 65536, tb + 1, 1, "4", 1);
    TILE(65536, 98304, tb + 2, 1, "4", 1);
    TILE(98304, 0,     tb + 3, 1, "4", 1);
  }
  // tail: tiles 92..95 (95&3 == 3)
  TILE(0,     32768, NT - 4, 1, "4", 1);   // stages tile 95
  TILE(32768, 65536, NT - 3, 0, "0", 1);   // certify buf(95)
  TILE(65536, 98304, NT - 2, 0, "0", 1);
  TILE(98304, 0,     NT - 1, 0, "0", 0);   // no next reads; lgkm(0)

  // Epilogue: s = (x_sq - 2*dot) + w_sq (reference fp32 rounding order).
  // 32x32 C/D (m74/m101, r2/r9/r10-validated): col = lane&31,
  // row = (reg&3) + 8*(reg>>2) + 4*(lane>>5).
#pragma unroll
  for (int m = 0; m < 4; ++m) {
#pragma unroll
    for (int rg = 0; rg < 16; ++rg) {
      const int row = brow + wm * 128 + m * 32 + (rg & 3) + 8 * (rg >> 2) + 4 * kh;
      const float xs = xsq[row];
      unsigned long long best = ~0ULL;
#pragma unroll
      for (int n = 0; n < 2; ++n) {
        const int col = bcol + wn * 64 + n * 32 + c31;
        const float s = (xs - 2.0f * acc[m][n][rg]) + wsq[col];
        unsigned ub = __float_as_uint(s);
        ub = (ub & 0x80000000u) ? ~ub : (ub | 0x80000000u);
        const unsigned long long key =
            ((unsigned long long)ub << 32) | (unsigned)col;
        if (key < best) best = key;
      }
#pragma unroll
      for (int o = 1; o < 32; o <<= 1) {   // reduce within each 32-lane half
        const unsigned long long v = __shfl_xor(best, o);
        if (v < best) best = v;
      }
      if (c31 == 0) atomicMin(&keys[row], best);
    }
  }
}

// ---- transpose G [O,H] -> GT [H,O] ----
__global__ __launch_bounds__(256) void transposeG_kernel(
    const float* __restrict__ G, float* __restrict__ GT)
{
  __shared__ float tile[32][33];
  const int h0 = blockIdx.x * 32;
  const int o0 = blockIdx.y * 32;
  const int tx = threadIdx.x;
  const int ty = threadIdx.y;
#pragma unroll
  for (int j = 0; j < 4; ++j) {
    const int o = o0 + ty + j * 8;
    if (o < O_) tile[ty + j * 8][tx] = G[(size_t)o * H_ + h0 + tx];
  }
  __syncthreads();
  const int o = o0 + tx;
  if (o < O_) {
#pragma unroll
    for (int j = 0; j < 4; ++j)
      GT[(size_t)(h0 + ty + j * 8) * O_ + o] = tile[tx][ty + j * 8];
  }
}

// ---- winners + row gather ----
__global__ __launch_bounds__(256) void finalize_kernel(
    const unsigned long long* __restrict__ keys,
    const float* __restrict__ GT, float* __restrict__ out)
{
  const int b = blockIdx.x;
  const unsigned w = (unsigned)(keys[b] & 0xFFFFFFFFull);
  if (threadIdx.x == 0) out[(size_t)B_ * O_ + b] = (float)w;
  const float4* src = (const float4*)(GT + (size_t)w * O_);
  float4* dst = (float4*)(out + (size_t)b * O_);
  for (int i = threadIdx.x; i < O_ / 4; i += 256) dst[i] = src[i];
}

extern "C" void kernel_launch(void* const* d_in, const int* in_sizes, int n_in,
                              void* d_out, int out_size, void* d_ws, size_t ws_size,
                              hipStream_t stream)
{
  (void)in_sizes; (void)n_in; (void)out_size; (void)ws_size;
  const float* x = (const float*)d_in[0];
  const float* kw = (const float*)d_in[1];
  const float* gw = (const float*)d_in[2];
  float* out = (float*)d_out;

  char* ws = (char*)d_ws;
  // A' 16.78MB | B' 33.55MB | xsq 16KB | wsq 32KB | keys 32KB ; GT overlays A'/B'
  __hip_bfloat16* Ap = (__hip_bfloat16*)(ws);
  __hip_bfloat16* Bp = (__hip_bfloat16*)(ws + 16777216);
  float* xsq = (float*)(ws + 50331648);
  float* wsq = (float*)(ws + 50331648 + 16384);
  unsigned long long* keys = (unsigned long long*)(ws + 50331648 + 16384 + 32768);
  float* GT = (float*)(ws);  // dead A'/B' space after GEMM

  split_all_kernel<<<B_ + H_, 256, 0, stream>>>(x, kw, Ap, Bp, xsq, wsq, keys);
  gemm_argmin_kernel<<<512, 512, 0, stream>>>(Ap, Bp, xsq, wsq, keys);
  transposeG_kernel<<<dim3(H_ / 32, (O_ + 31) / 32), dim3(32, 8), 0, stream>>>(gw, GT);
  finalize_kernel<<<B_, 256, 0, stream>>>(keys, GT, out);
}